// Round 1
// baseline (643.938 us; speedup 1.0000x reference)
//
#include <hip/hip_runtime.h>

// ---------------- constants ----------------
// M = 9 (lmax=2), NB = 32 channels, NRBF = 20, CUTOFF = 5, T = 2
#define CHUNK 16   // edges per 32-lane group in edge kernel

__device__ __constant__ double FACT[8] = {1.,1.,2.,6.,24.,120.,720.,5040.};

// ---------------- CG build (exact replica of reference, double precision) ----
__device__ double cg_cplx(int j1,int m1,int j2,int m2,int j3,int m3){
  if (m3 != m1+m2 || j3 < abs(j1-j2) || j3 > j1+j2) return 0.0;
  double pref = sqrt((2.0*j3+1.0)*FACT[j1+j2-j3]*FACT[j1-j2+j3]*FACT[-j1+j2+j3]/FACT[j1+j2+j3+1]);
  pref *= sqrt(FACT[j1+m1]*FACT[j1-m1]*FACT[j2+m2]*FACT[j2-m2]*FACT[j3+m3]*FACT[j3-m3]);
  int kmin = max(0, max(j2-j3-m1, j1+m2-j3));
  int kmax = min(j1+j2-j3, min(j1-m1, j2+m2));
  double s = 0.0;
  for (int k=kmin; k<=kmax; ++k){
    double t = 1.0/(FACT[k]*FACT[j1+j2-j3-k]*FACT[j1-m1-k]*FACT[j2+m2-k]*FACT[j3-j2+m1+k]*FACT[j3-j1-m2+k]);
    s += (k&1)? -t : t;
  }
  return pref*s;
}

// row (real m) of the complex->real transform U^l: up to 2 nonzero columns
__device__ int u_row(int m, int* mc, double* re, double* im){
  const double is2 = 0.70710678118654752440;
  if (m==0){ mc[0]=0; re[0]=1.0; im[0]=0.0; return 1; }
  if (m>0){ mc[0]=m;  re[0]=((m&1)? -is2 : is2); im[0]=0.0;
            mc[1]=-m; re[1]=is2;                 im[1]=0.0; return 2; }
  int mu=-m;
  mc[0]=m;  re[0]=0.0; im[0]=is2;
  mc[1]=mu; re[1]=0.0; im[1]=((mu&1)? is2 : -is2);
  return 2;
}

__global__ void build_cg_kernel(float* __restrict__ cg){
  int idx = blockIdx.x*blockDim.x + threadIdx.x;
  if (idx >= 729) return;
  int a = idx/81, b = (idx/9)%9, c = idx%9;
  int l1 = (a==0)?0:((a<4)?1:2); int m1 = a - (l1*l1+l1);
  int l2 = (b==0)?0:((b<4)?1:2); int m2 = b - (l2*l2+l2);
  int l3 = (c==0)?0:((c<4)?1:2); int m3 = c - (l3*l3+l3);
  float out = 0.f;
  bool ok = (((l1+l2+l3)&1)==0) && (l3 >= abs(l1-l2)) && (l3 <= l1+l2);
  if (ok){
    int mca[2],mcb[2],mcc[2]; double ar[2],ai[2],br[2],bi[2],cr[2],ci[2];
    int na=u_row(m1,mca,ar,ai), nb=u_row(m2,mcb,br,bi), nc=u_row(m3,mcc,cr,ci);
    double acc=0.0;
    for (int i=0;i<na;i++) for (int j=0;j<nb;j++){
      double zr = ar[i]*br[j]-ai[i]*bi[j];
      double zi = ar[i]*bi[j]+ai[i]*br[j];
      for (int k=0;k<nc;k++){
        // times conj(zc): real part = zr*cr + zi*ci
        double rp = zr*cr[k] + zi*ci[k];
        if (rp != 0.0) acc += rp*cg_cplx(l1,mca[i],l2,mcb[j],l3,mcc[k]);
      }
    }
    out = (float)acc;
  }
  cg[idx] = out;
}

// ---------------- x init: x[:,0,:] = emb[Z], rest 0 ----------------
__global__ void init_x_kernel(const int* __restrict__ Z, const float* __restrict__ emb,
                              float* __restrict__ x, int n_atoms){
  int i = blockIdx.x*blockDim.x + threadIdx.x;
  if (i >= n_atoms*288) return;
  int rem = i % 288;
  float val = 0.f;
  if (rem < 32){
    int atom = i / 288;
    val = emb[Z[atom]*32 + rem];
  }
  x[i] = val;
}

// ---------------- edge kernel ----------------
// 256 threads = 8 groups of 32 lanes; lane = channel n; each group does CHUNK
// consecutive edges, register-accumulating over sorted-idx_i runs, atomicAdd
// flush on run change.
__global__ __launch_bounds__(256) void edge_kernel(
    const float* __restrict__ r_ij, const int* __restrict__ idx_i, const int* __restrict__ idx_j,
    const float* __restrict__ x, const float* __restrict__ Wf_t, const float* __restrict__ bf_t,
    const float* __restrict__ cg_g, float* __restrict__ dx, int n_edges)
{
  __shared__ float cg_s[729];
  __shared__ __align__(16) float tbc[8][112];   // tbc[g][c*12 + b], rows padded to 12
  int tid = threadIdx.x;
  for (int i = tid; i < 729; i += 256) cg_s[i] = cg_g[i];
  __syncthreads();

  int g = tid >> 5, lane = tid & 31;

  // per-lane filter weights in registers (reused across all edges)
  float wfr[3][20]; float bfl[3];
  #pragma unroll
  for (int l=0;l<3;l++){
    const float* rp = Wf_t + (l*32+lane)*20;   // 80B rows -> 16B aligned
    #pragma unroll
    for (int q=0;q<5;q++){
      float4 v4 = *reinterpret_cast<const float4*>(rp + q*4);
      wfr[l][q*4+0]=v4.x; wfr[l][q*4+1]=v4.y; wfr[l][q*4+2]=v4.z; wfr[l][q*4+3]=v4.w;
    }
    bfl[l] = bf_t[l*32+lane];
  }

  const float STEP  = 5.0f/19.0f;
  const float ALPHA = -0.5f/(STEP*STEP);

  float racc[9];
  #pragma unroll
  for (int c=0;c<9;c++) racc[c]=0.f;
  int cur_i = -1;
  int base = (blockIdx.x*8 + g)*CHUNK;

  for (int k=0;k<CHUNK;k++){
    int e = base + k;
    if (e >= n_edges) break;           // uniform within the group

    float rx = r_ij[e*3+0], ry = r_ij[e*3+1], rz = r_ij[e*3+2];
    float dd = sqrtf(rx*rx+ry*ry+rz*rz);
    float inv = 1.0f/dd;
    float X = rx*inv, Yv = ry*inv, Zv = rz*inv;
    const float c1 = 0.4886025119029199f, c2 = 1.0925484305920792f;
    float Y[9];
    Y[0]=0.28209479177387814f; Y[1]=c1*Yv; Y[2]=c1*Zv; Y[3]=c1*X;
    Y[4]=c2*X*Yv; Y[5]=c2*Yv*Zv; Y[6]=0.31539156525252005f*(3.f*Zv*Zv-1.f);
    Y[7]=c2*X*Zv; Y[8]=0.5462742152960396f*(X*X-Yv*Yv);

    // per-edge filter Wl[l][lane]
    float wl0=bfl[0], wl1=bfl[1], wl2=bfl[2];
    #pragma unroll
    for (int r=0;r<20;r++){
      float dt = dd - r*STEP;
      float rb = __expf(ALPHA*dt*dt);
      wl0 += rb*wfr[0][r]; wl1 += rb*wfr[1][r]; wl2 += rb*wfr[2][r];
    }
    float fc = (dd < 5.0f) ? 0.5f*(cosf(dd*0.6283185307179586f)+1.0f) : 0.0f;
    wl0*=fc; wl1*=fc; wl2*=fc;

    // tbc[c][b] = sum_a Y[a] * CG[a,b,c]   (shared within the 32-lane group;
    // same-wave LDS write->read, no barrier needed)
    for (int s=lane; s<108; s+=32){
      int cc = s/12, bb = s - cc*12;
      float tv = 0.f;
      if (bb < 9){
        #pragma unroll
        for (int a2=0;a2<9;a2++) tv += Y[a2]*cg_s[a2*81 + bb*9 + cc];
      }
      tbc[g][s] = tv;
    }

    int j  = idx_j[e];
    int ii = idx_i[e];
    const float* xp = x + j*288 + lane;
    float xj[9];
    #pragma unroll
    for (int b2=0;b2<9;b2++) xj[b2] = xp[b2*32];

    if (ii != cur_i){
      if (cur_i >= 0){
        float* dp = dx + cur_i*288 + lane;
        #pragma unroll
        for (int c=0;c<9;c++){ atomicAdd(dp + c*32, racc[c]); racc[c]=0.f; }
      }
      cur_i = ii;
    }

    const float4* tb4 = reinterpret_cast<const float4*>(&tbc[g][0]);
    #pragma unroll
    for (int c=0;c<9;c++){
      float4 t0 = tb4[c*3+0];
      float4 t1 = tb4[c*3+1];
      float  t2 = tbc[g][c*12+8];
      float acc = t0.x*xj[0]+t0.y*xj[1]+t0.z*xj[2]+t0.w*xj[3]
                + t1.x*xj[4]+t1.y*xj[5]+t1.z*xj[6]+t1.w*xj[7]
                + t2*xj[8];
      float w = (c==0)? wl0 : ((c<4)? wl1 : wl2);
      racc[c] += w*acc;
    }
  }
  if (cur_i >= 0){
    float* dp = dx + cur_i*288 + lane;
    #pragma unroll
    for (int c=0;c<9;c++) atomicAdd(dp + c*32, racc[c]);
  }
}

// ---------------- atom kernel ----------------
__device__ __forceinline__ constexpr int lof(int a){ return (a==0)?0:((a<4)?1:2); }
__device__ __forceinline__ constexpr bool cg_nz(int l1,int l2,int l3){
  int d = (l1>l2)?(l1-l2):(l2-l1);
  return (((l1+l2+l3)&1)==0) && (l3 >= d) && (l3 <= l1+l2);
}

__global__ __launch_bounds__(256) void atom_kernel(
    float* __restrict__ x, const float* __restrict__ dxg,
    const float* __restrict__ cg_g,
    const float* __restrict__ Wm1_t, const float* __restrict__ Wm2_t, const float* __restrict__ Wm3_t,
    const float* __restrict__ Wg_t, const float* __restrict__ bg_t, int n_atoms)
{
  __shared__ float W1T[1024], W2T[1024], W3T[1024];   // WT[n*32+k] = W[k*32+n]
  __shared__ float WgT[3072];                          // WgT[n*96+j] = Wg[j*32+n]
  __shared__ float bgs[96];
  __shared__ __align__(16) float CGp[81*12];           // CGp[(a*9+b)*12 + c], pads 0
  __shared__ __align__(16) float tile[8][288];
  int tid = threadIdx.x;
  for (int i=tid;i<1024;i+=256){ int n=i>>5, kk=i&31; W1T[i]=Wm1_t[kk*32+n]; W2T[i]=Wm2_t[kk*32+n]; W3T[i]=Wm3_t[kk*32+n]; }
  for (int i=tid;i<3072;i+=256){ int n=i/96, jj=i-n*96; WgT[i]=Wg_t[jj*32+n]; }
  for (int i=tid;i<96;i+=256) bgs[i]=bg_t[i];
  for (int i=tid;i<81*12;i+=256){ int ab=i/12, cc=i-ab*12; CGp[i]=(cc<9)? cg_g[ab*9+cc] : 0.f; }
  __syncthreads();

  int g = tid>>5, k = tid&31;
  int atom = blockIdx.x*8 + g;
  if (atom >= n_atoms) return;
  float* tg = &tile[g][0];

  const float* dp = dxg + atom*288 + k;
  float v[9];
  #pragma unroll
  for (int c=0;c<9;c++){ v[c]=dp[c*32]; tg[c*32+k]=v[c]; }

  // ddx = dx @ Wm1^T   (lane k = output channel)
  float wr[32];
  #pragma unroll
  for (int n=0;n<32;n++) wr[n]=W1T[n*32+k];
  float u[9];
  #pragma unroll
  for (int c=0;c<9;c++){
    float s=0.f;
    #pragma unroll
    for (int n=0;n<32;n++) s += tg[c*32+n]*wr[n];
    u[c]=s;
  }

  // w[c] = v[c] + sum_{a,b} CG[a,b,c] v[a] u[b]   (block sparsity is exact)
  float w[9];
  #pragma unroll
  for (int c=0;c<9;c++) w[c]=v[c];
  #pragma unroll
  for (int a=0;a<9;a++){
    #pragma unroll
    for (int b=0;b<9;b++){
      const int l1=lof(a), l2=lof(b);
      float prod = v[a]*u[b];
      const int bo = (a*9+b)*12;
      if (cg_nz(l1,l2,0)){ w[0] += CGp[bo+0]*prod; }
      if (cg_nz(l1,l2,1)){ w[1]+=CGp[bo+1]*prod; w[2]+=CGp[bo+2]*prod; w[3]+=CGp[bo+3]*prod; }
      if (cg_nz(l1,l2,2)){ w[4]+=CGp[bo+4]*prod; w[5]+=CGp[bo+5]*prod; w[6]+=CGp[bo+6]*prod;
                           w[7]+=CGp[bo+7]*prod; w[8]+=CGp[bo+8]*prod; }
    }
  }

  // p = w @ Wm2^T
  #pragma unroll
  for (int c=0;c<9;c++) tg[c*32+k]=w[c];
  #pragma unroll
  for (int n=0;n<32;n++) wr[n]=W2T[n*32+k];
  float p[9];
  #pragma unroll
  for (int c=0;c<9;c++){
    float s=0.f;
    #pragma unroll
    for (int n=0;n<32;n++) s += tg[c*32+n]*wr[n];
    p[c]=s;
  }

  // gate from p[0,:]
  tg[k] = p[0];
  float t0r[32];
  #pragma unroll
  for (int n=0;n<32;n++) t0r[n] = tg[n];
  float s0=bgs[k], s1=bgs[32+k], s2=bgs[64+k];
  #pragma unroll
  for (int n=0;n<32;n++){
    float tv=t0r[n];
    s0 += tv*WgT[n*96 + k];
    s1 += tv*WgT[n*96 + 32 + k];
    s2 += tv*WgT[n*96 + 64 + k];
  }
  float h0 = 1.f/(1.f+__expf(-s0));
  float h1 = 1.f/(1.f+__expf(-s1));
  float h2 = 1.f/(1.f+__expf(-s2));

  float q[9];
  #pragma unroll
  for (int c=0;c<9;c++){ float hh = (c==0)?h0:((c<4)?h1:h2); q[c]=p[c]*hh; }

  // r = q @ Wm3^T ; x += r
  #pragma unroll
  for (int c=0;c<9;c++) tg[c*32+k]=q[c];
  #pragma unroll
  for (int n=0;n<32;n++) wr[n]=W3T[n*32+k];
  float* xo = x + atom*288 + k;
  #pragma unroll
  for (int c=0;c<9;c++){
    float s=0.f;
    #pragma unroll
    for (int n=0;n<32;n++) s += tg[c*32+n]*wr[n];
    xo[c*32] += s;
  }
}

// ---------------- launch ----------------
extern "C" void kernel_launch(void* const* d_in, const int* in_sizes, int n_in,
                              void* d_out, int out_size, void* d_ws, size_t ws_size,
                              hipStream_t stream)
{
  const int*   Z    = (const int*)d_in[0];
  const float* r_ij = (const float*)d_in[1];
  const int*   idxi = (const int*)d_in[2];
  const int*   idxj = (const int*)d_in[3];
  const float* emb  = (const float*)d_in[4];
  const float* Wf   = (const float*)d_in[5];
  const float* bf   = (const float*)d_in[6];
  const float* Wm1  = (const float*)d_in[7];
  const float* Wm2  = (const float*)d_in[8];
  const float* Wm3  = (const float*)d_in[9];
  const float* Wg   = (const float*)d_in[10];
  const float* bg   = (const float*)d_in[11];
  int n_atoms = in_sizes[0];
  int n_edges = in_sizes[1]/3;

  float* x     = (float*)d_out;
  float* cg_ws = (float*)d_ws;
  float* dx    = (float*)((char*)d_ws + 4096);

  build_cg_kernel<<<3,256,0,stream>>>(cg_ws);
  init_x_kernel<<<(n_atoms*288+255)/256,256,0,stream>>>(Z, emb, x, n_atoms);

  for (int t=0;t<2;t++){
    hipMemsetAsync(dx, 0, (size_t)n_atoms*288*sizeof(float), stream);
    int eblocks = (n_edges + 8*CHUNK - 1)/(8*CHUNK);
    edge_kernel<<<eblocks,256,0,stream>>>(r_ij, idxi, idxj, x,
                                          Wf + t*96*20, bf + t*96, cg_ws, dx, n_edges);
    atom_kernel<<<(n_atoms+7)/8,256,0,stream>>>(x, dx, cg_ws,
                                          Wm1 + t*1024, Wm2 + t*1024, Wm3 + t*1024,
                                          Wg + t*96*32, bg + t*96, n_atoms);
  }
}

// Round 2
// 470.850 us; speedup vs baseline: 1.3676x; 1.3676x over previous
//
#include <hip/hip_runtime.h>

// M = 9 (lmax=2), NB = 32 channels, NRBF = 20, CUTOFF = 5, T = 2
#define CHUNK 16   // edges per 32-lane group in edge kernel

// ====================== compile-time CG table ======================
constexpr double CFACT[8] = {1.,1.,2.,6.,24.,120.,720.,5040.};

constexpr double csqrt(double x){
  if (x <= 0.0) return 0.0;
  double s = 1.0;
  while (x > 4.0)  { x *= 0.25; s *= 2.0; }
  while (x < 0.25) { x *= 4.0;  s *= 0.5; }
  double g = 1.0;
  for (int i=0;i<10;i++) g = 0.5*(g + x/g);
  return s*g;
}

constexpr double cg_complex(int j1,int m1,int j2,int m2,int j3,int m3){
  if (m3 != m1+m2 || j3 < (j1>j2?j1-j2:j2-j1) || j3 > j1+j2) return 0.0;
  double pref = csqrt((2.0*j3+1.0)*CFACT[j1+j2-j3]*CFACT[j1-j2+j3]*CFACT[-j1+j2+j3]/CFACT[j1+j2+j3+1]);
  pref *= csqrt(CFACT[j1+m1]*CFACT[j1-m1]*CFACT[j2+m2]*CFACT[j2-m2]*CFACT[j3+m3]*CFACT[j3-m3]);
  int kmin = 0;
  if (j2-j3-m1 > kmin) kmin = j2-j3-m1;
  if (j1+m2-j3 > kmin) kmin = j1+m2-j3;
  int kmax = j1+j2-j3;
  if (j1-m1 < kmax) kmax = j1-m1;
  if (j2+m2 < kmax) kmax = j2+m2;
  double s = 0.0;
  for (int k=kmin;k<=kmax;++k){
    double t = 1.0/(CFACT[k]*CFACT[j1+j2-j3-k]*CFACT[j1-m1-k]*CFACT[j2+m2-k]*CFACT[j3-j2+m1+k]*CFACT[j3-j1-m2+k]);
    s += (k&1)? -t : t;
  }
  return pref*s;
}

struct UR { int n; int mc[2]; double re[2]; double im[2]; };
constexpr UR u_row(int m){
  UR u{}; const double is2 = 0.70710678118654752440;
  if (m==0){ u.n=1; u.mc[0]=0; u.re[0]=1.0; u.im[0]=0.0; u.mc[1]=0; u.re[1]=0.0; u.im[1]=0.0; }
  else if (m>0){ u.n=2; u.mc[0]=m;  u.re[0]=((m&1)? -is2:is2); u.im[0]=0.0;
                        u.mc[1]=-m; u.re[1]=is2;               u.im[1]=0.0; }
  else { int mu=-m; u.n=2; u.mc[0]=m;  u.re[0]=0.0; u.im[0]=is2;
                           u.mc[1]=mu; u.re[1]=0.0; u.im[1]=((mu&1)? is2:-is2); }
  return u;
}

struct CGTab { float v[9][9][9]; };
constexpr CGTab build_cg(){
  CGTab g{};
  // complex CG table, packed index l*l+l+m
  double cc[9][9][9] = {};
  for (int a=0;a<9;a++){
    int l1 = (a==0)?0:((a<4)?1:2); int m1 = a - (l1*l1+l1);
    for (int b=0;b<9;b++){
      int l2 = (b==0)?0:((b<4)?1:2); int m2 = b - (l2*l2+l2);
      int m3 = m1+m2;
      for (int l3=0;l3<=2;l3++){
        if (m3 < -l3 || m3 > l3) continue;
        cc[a][b][l3*l3+l3+m3] = cg_complex(l1,m1,l2,m2,l3,m3);
      }
    }
  }
  // real transform, only parity/triangle-valid blocks (others stay zero)
  for (int l1=0;l1<=2;l1++) for (int l2=0;l2<=2;l2++) for (int l3=0;l3<=2;l3++){
    if (((l1+l2+l3)&1)==1) continue;
    int dl = (l1>l2)?(l1-l2):(l2-l1);
    if (l3 < dl || l3 > l1+l2) continue;
    for (int m1=-l1;m1<=l1;m1++) for (int m2=-l2;m2<=l2;m2++) for (int m3=-l3;m3<=l3;m3++){
      UR ua = u_row(m1), ub = u_row(m2), uc = u_row(m3);
      double acc = 0.0;
      for (int i=0;i<ua.n;i++) for (int j=0;j<ub.n;j++){
        double zr = ua.re[i]*ub.re[j] - ua.im[i]*ub.im[j];
        double zi = ua.re[i]*ub.im[j] + ua.im[i]*ub.re[j];
        for (int k=0;k<uc.n;k++){
          double rp = zr*uc.re[k] + zi*uc.im[k];   // Re[(za*zb)*conj(zc)]
          if (rp != 0.0)
            acc += rp * cc[l1*l1+l1+ua.mc[i]][l2*l2+l2+ub.mc[j]][l3*l3+l3+uc.mc[k]];
        }
      }
      g.v[l1*l1+l1+m1][l2*l2+l2+m2][l3*l3+l3+m3] = (float)acc;
    }
  }
  return g;
}
constexpr CGTab CGT = build_cg();

// ---------------- x init: x[:,0,:] = emb[Z], rest 0; also zero dx ----------
__global__ void init_x_kernel(const int* __restrict__ Z, const float* __restrict__ emb,
                              float* __restrict__ x, float* __restrict__ dx, int n_atoms){
  int i = blockIdx.x*blockDim.x + threadIdx.x;
  if (i >= n_atoms*288) return;
  int rem = i % 288;
  float val = 0.f;
  if (rem < 32){
    int atom = i / 288;
    val = emb[Z[atom]*32 + rem];
  }
  x[i] = val;
  dx[i] = 0.f;
}

// ---------------- edge kernel ----------------
// 256 threads = 8 groups of 32 lanes; lane = channel n; each group does CHUNK
// consecutive edges, register-accumulating over sorted-idx_i runs, atomicAdd
// flush on run change. CG is compile-time sparse -> pure immediate FMAs.
__global__ __launch_bounds__(256) void edge_kernel(
    const float* __restrict__ r_ij, const int* __restrict__ idx_i, const int* __restrict__ idx_j,
    const float* __restrict__ x, const float* __restrict__ Wf_t, const float* __restrict__ bf_t,
    float* __restrict__ dx, int n_edges)
{
  int tid = threadIdx.x;
  int g = tid >> 5, lane = tid & 31;

  // per-lane filter weights in registers (reused across all edges)
  float wfr[3][20]; float bfl[3];
  #pragma unroll
  for (int l=0;l<3;l++){
    const float* rp = Wf_t + (l*32+lane)*20;   // 80B rows -> 16B aligned
    #pragma unroll
    for (int q=0;q<5;q++){
      float4 v4 = *reinterpret_cast<const float4*>(rp + q*4);
      wfr[l][q*4+0]=v4.x; wfr[l][q*4+1]=v4.y; wfr[l][q*4+2]=v4.z; wfr[l][q*4+3]=v4.w;
    }
    bfl[l] = bf_t[l*32+lane];
  }

  const float STEP  = 5.0f/19.0f;
  const float ALPHA = -0.5f/(STEP*STEP);
  float myoff = (float)lane * STEP;   // lane >= 20: exp underflows to 0, harmless

  float racc[9];
  #pragma unroll
  for (int c=0;c<9;c++) racc[c]=0.f;
  int cur_i = -1;
  int base = (blockIdx.x*8 + g)*CHUNK;

  for (int k=0;k<CHUNK;k++){
    int e = base + k;
    if (e >= n_edges) break;           // uniform within the group

    float rx = r_ij[e*3+0], ry = r_ij[e*3+1], rz = r_ij[e*3+2];
    int j  = idx_j[e];
    int ii = idx_i[e];

    float d2 = fmaf(rx,rx,fmaf(ry,ry,rz*rz));
    float dd = sqrtf(d2);
    float inv = __fdividef(1.0f, dd);
    float X = rx*inv, Yv = ry*inv, Zv = rz*inv;
    const float c1 = 0.4886025119029199f, c2 = 1.0925484305920792f;
    float Y[9];
    Y[0]=0.28209479177387814f; Y[1]=c1*Yv; Y[2]=c1*Zv; Y[3]=c1*X;
    Y[4]=c2*X*Yv; Y[5]=c2*Yv*Zv; Y[6]=0.31539156525252005f*(3.f*Zv*Zv-1.f);
    Y[7]=c2*X*Zv; Y[8]=0.5462742152960396f*(X*X-Yv*Yv);

    // RBF: lane r computes its own basis value, broadcast via shuffle
    float dtl = dd - myoff;
    float rbl = __expf(ALPHA*dtl*dtl);
    float wl0=bfl[0], wl1=bfl[1], wl2=bfl[2];
    #pragma unroll
    for (int r=0;r<20;r++){
      float rb = __shfl(rbl, r, 32);
      wl0 = fmaf(rb, wfr[0][r], wl0);
      wl1 = fmaf(rb, wfr[1][r], wl1);
      wl2 = fmaf(rb, wfr[2][r], wl2);
    }
    float fc = (dd < 5.0f) ? 0.5f*(__cosf(dd*0.6283185307179586f)+1.0f) : 0.0f;
    wl0*=fc; wl1*=fc; wl2*=fc;

    const float* xp = x + j*288 + lane;
    float xj[9];
    #pragma unroll
    for (int b2=0;b2<9;b2++) xj[b2] = xp[b2*32];

    if (ii != cur_i){
      if (cur_i >= 0){
        float* dp = dx + cur_i*288 + lane;
        #pragma unroll
        for (int c=0;c<9;c++){ atomicAdd(dp + c*32, racc[c]); racc[c]=0.f; }
      }
      cur_i = ii;
    }

    // yv[c] = sum_{a,b} Y[a] * CG[a][b][c] * xj[b]  (compile-time sparse)
    float yv[9];
    #pragma unroll
    for (int c=0;c<9;c++) yv[c]=0.f;
    #pragma unroll
    for (int a=0;a<9;a++){
      #pragma unroll
      for (int b=0;b<9;b++){
        bool any = false;
        #pragma unroll
        for (int c=0;c<9;c++) any = any | (CGT.v[a][b][c] != 0.f);
        if (any){
          float p = Y[a]*xj[b];
          #pragma unroll
          for (int c=0;c<9;c++){
            if (CGT.v[a][b][c] != 0.f) yv[c] = fmaf(CGT.v[a][b][c], p, yv[c]);
          }
        }
      }
    }
    racc[0] = fmaf(wl0, yv[0], racc[0]);
    #pragma unroll
    for (int c=1;c<4;c++) racc[c] = fmaf(wl1, yv[c], racc[c]);
    #pragma unroll
    for (int c=4;c<9;c++) racc[c] = fmaf(wl2, yv[c], racc[c]);
  }
  if (cur_i >= 0){
    float* dp = dx + cur_i*288 + lane;
    #pragma unroll
    for (int c=0;c<9;c++) atomicAdd(dp + c*32, racc[c]);
  }
}

// ---------------- atom kernel ----------------
__global__ __launch_bounds__(256) void atom_kernel(
    float* __restrict__ x, float* __restrict__ dxg,
    const float* __restrict__ Wm1_t, const float* __restrict__ Wm2_t, const float* __restrict__ Wm3_t,
    const float* __restrict__ Wg_t, const float* __restrict__ bg_t, int n_atoms)
{
  __shared__ float W1T[1024], W2T[1024], W3T[1024];   // WT[n*32+k] = W[k*32+n]
  __shared__ float WgT[3072];                          // WgT[n*96+j] = Wg[j*32+n]
  __shared__ float bgs[96];
  __shared__ __align__(16) float tile[8][288];
  int tid = threadIdx.x;
  for (int i=tid;i<1024;i+=256){ int n=i>>5, kk=i&31; W1T[i]=Wm1_t[kk*32+n]; W2T[i]=Wm2_t[kk*32+n]; W3T[i]=Wm3_t[kk*32+n]; }
  for (int i=tid;i<3072;i+=256){ int n=i/96, jj=i-n*96; WgT[i]=Wg_t[jj*32+n]; }
  for (int i=tid;i<96;i+=256) bgs[i]=bg_t[i];
  __syncthreads();

  int g = tid>>5, k = tid&31;
  int atom = blockIdx.x*8 + g;
  if (atom >= n_atoms) return;
  float* tg = &tile[g][0];
  const float4* t4 = reinterpret_cast<const float4*>(tg);

  float* dp = dxg + atom*288 + k;
  float v[9];
  #pragma unroll
  for (int c=0;c<9;c++){ v[c]=dp[c*32]; tg[c*32+k]=v[c]; dp[c*32]=0.f; }  // consume + re-zero for next round

  // ddx = dx @ Wm1^T   (lane k = output channel)
  float wr[32];
  #pragma unroll
  for (int n=0;n<32;n++) wr[n]=W1T[n*32+k];
  float u[9];
  #pragma unroll
  for (int c=0;c<9;c++){
    float s=0.f;
    #pragma unroll
    for (int q=0;q<8;q++){
      float4 tv = t4[c*8+q];
      s = fmaf(tv.x, wr[4*q+0], s); s = fmaf(tv.y, wr[4*q+1], s);
      s = fmaf(tv.z, wr[4*q+2], s); s = fmaf(tv.w, wr[4*q+3], s);
    }
    u[c]=s;
  }

  // w[c] = v[c] + sum_{a,b} CG[a][b][c] v[a] u[b]  (compile-time sparse)
  float w[9];
  #pragma unroll
  for (int c=0;c<9;c++) w[c]=v[c];
  #pragma unroll
  for (int a=0;a<9;a++){
    #pragma unroll
    for (int b=0;b<9;b++){
      bool any = false;
      #pragma unroll
      for (int c=0;c<9;c++) any = any | (CGT.v[a][b][c] != 0.f);
      if (any){
        float p = v[a]*u[b];
        #pragma unroll
        for (int c=0;c<9;c++){
          if (CGT.v[a][b][c] != 0.f) w[c] = fmaf(CGT.v[a][b][c], p, w[c]);
        }
      }
    }
  }

  // p = w @ Wm2^T
  #pragma unroll
  for (int c=0;c<9;c++) tg[c*32+k]=w[c];
  #pragma unroll
  for (int n=0;n<32;n++) wr[n]=W2T[n*32+k];
  float p[9];
  #pragma unroll
  for (int c=0;c<9;c++){
    float s=0.f;
    #pragma unroll
    for (int q=0;q<8;q++){
      float4 tv = t4[c*8+q];
      s = fmaf(tv.x, wr[4*q+0], s); s = fmaf(tv.y, wr[4*q+1], s);
      s = fmaf(tv.z, wr[4*q+2], s); s = fmaf(tv.w, wr[4*q+3], s);
    }
    p[c]=s;
  }

  // gate from p[0,:]
  tg[k] = p[0];
  float s0=bgs[k], s1=bgs[32+k], s2=bgs[64+k];
  #pragma unroll
  for (int q=0;q<8;q++){
    float4 tv = t4[q];
    #pragma unroll
    for (int z=0;z<4;z++){
      float tvz = (z==0)?tv.x:((z==1)?tv.y:((z==2)?tv.z:tv.w));
      int n = 4*q+z;
      s0 = fmaf(tvz, WgT[n*96 + k],      s0);
      s1 = fmaf(tvz, WgT[n*96 + 32 + k], s1);
      s2 = fmaf(tvz, WgT[n*96 + 64 + k], s2);
    }
  }
  float h0 = 1.f/(1.f+__expf(-s0));
  float h1 = 1.f/(1.f+__expf(-s1));
  float h2 = 1.f/(1.f+__expf(-s2));

  float q9[9];
  q9[0]=p[0]*h0;
  #pragma unroll
  for (int c=1;c<4;c++) q9[c]=p[c]*h1;
  #pragma unroll
  for (int c=4;c<9;c++) q9[c]=p[c]*h2;

  // r = q @ Wm3^T ; x += r
  #pragma unroll
  for (int c=0;c<9;c++) tg[c*32+k]=q9[c];
  #pragma unroll
  for (int n=0;n<32;n++) wr[n]=W3T[n*32+k];
  float* xo = x + atom*288 + k;
  #pragma unroll
  for (int c=0;c<9;c++){
    float s=0.f;
    #pragma unroll
    for (int q=0;q<8;q++){
      float4 tv = t4[c*8+q];
      s = fmaf(tv.x, wr[4*q+0], s); s = fmaf(tv.y, wr[4*q+1], s);
      s = fmaf(tv.z, wr[4*q+2], s); s = fmaf(tv.w, wr[4*q+3], s);
    }
    xo[c*32] += s;
  }
}

// ---------------- launch ----------------
extern "C" void kernel_launch(void* const* d_in, const int* in_sizes, int n_in,
                              void* d_out, int out_size, void* d_ws, size_t ws_size,
                              hipStream_t stream)
{
  const int*   Z    = (const int*)d_in[0];
  const float* r_ij = (const float*)d_in[1];
  const int*   idxi = (const int*)d_in[2];
  const int*   idxj = (const int*)d_in[3];
  const float* emb  = (const float*)d_in[4];
  const float* Wf   = (const float*)d_in[5];
  const float* bf   = (const float*)d_in[6];
  const float* Wm1  = (const float*)d_in[7];
  const float* Wm2  = (const float*)d_in[8];
  const float* Wm3  = (const float*)d_in[9];
  const float* Wg   = (const float*)d_in[10];
  const float* bg   = (const float*)d_in[11];
  int n_atoms = in_sizes[0];
  int n_edges = in_sizes[1]/3;

  float* x  = (float*)d_out;
  float* dx = (float*)d_ws;

  init_x_kernel<<<(n_atoms*288+255)/256,256,0,stream>>>(Z, emb, x, dx, n_atoms);

  for (int t=0;t<2;t++){
    int eblocks = (n_edges + 8*CHUNK - 1)/(8*CHUNK);
    edge_kernel<<<eblocks,256,0,stream>>>(r_ij, idxi, idxj, x,
                                          Wf + t*96*20, bf + t*96, dx, n_edges);
    atom_kernel<<<(n_atoms+7)/8,256,0,stream>>>(x, dx,
                                          Wm1 + t*1024, Wm2 + t*1024, Wm3 + t*1024,
                                          Wg + t*96*32, bg + t*96, n_atoms);
  }
}